// Round 7
// baseline (8688.001 us; speedup 1.0000x reference)
//
#include <hip/hip_runtime.h>

#define HID   1024
#define BATCH 256
#define TSEQ  128
#define PRED  96
#define IND   7
#define OUTD  7
#define SK    10   // small input dim: 7 features + 3 time-encode dims

typedef __attribute__((ext_vector_type(8))) _Float16 f16x8;
typedef __attribute__((ext_vector_type(4))) float    f32x4;

#define BM   64
#define BN   64
#define GSTR 68    // gates LDS stride (floats), <=2-way bank aliasing (free)

__device__ __forceinline__ float sigmoidf_fast(float x) {
  return 1.0f / (1.0f + __expf(-x));
}
__device__ __forceinline__ float tanhf_fast(float x) {
  float ax = fabsf(x);
  float e  = __expf(-2.0f * ax);
  float r  = (1.0f - e) / (1.0f + e);
  return copysignf(r, x);
}

template<int AUX>
__device__ __forceinline__ void async_cp16(const void* g, void* l) {
  __builtin_amdgcn_global_load_lds(
      (const __attribute__((address_space(1))) void*)g,
      (__attribute__((address_space(3))) void*)l, 16, 0, AUX);
}

// fine-grained wait + barrier (pipeline)
#define WBAR(N) asm volatile("s_waitcnt vmcnt(" #N ")\n\ts_barrier" ::: "memory")
#define BARO()  asm volatile("s_barrier" ::: "memory")

// ---------------------------------------------------------------------------
// Weight prep: fp16 B [n][k], n = grp*64 + gate*16 + u <-> r = gate*1024+grp*16+u
// ---------------------------------------------------------------------------
__global__ __launch_bounds__(256) void prep_kernel(
    const float* __restrict__ Wih0, const float* __restrict__ Whh0,
    const float* __restrict__ bih0, const float* __restrict__ bhh0,
    const float* __restrict__ Wih1, const float* __restrict__ Whh1,
    const float* __restrict__ bih1, const float* __restrict__ bhh1,
    const float* __restrict__ Wih2, const float* __restrict__ Whh2,
    const float* __restrict__ bih2, const float* __restrict__ bhh2,
    _Float16* __restrict__ B0, _Float16* __restrict__ B1, _Float16* __restrict__ B2,
    float* __restrict__ W0p, float* __restrict__ biasP)
{
  size_t e = (size_t)blockIdx.x * 256 + threadIdx.x;
  const size_t S0 = (size_t)4096 * 1024;
  const size_t S1 = (size_t)4096 * 2048;
  if (e < S0) {
    int n = (int)(e >> 10), k = (int)(e & 1023);
    int nb = n >> 6, gate = (n >> 4) & 3, u = n & 15;
    int r = gate * 1024 + nb * 16 + u;
    B0[e] = (_Float16)Whh0[(size_t)r * 1024 + k];
  } else if (e < S0 + S1) {
    size_t q = e - S0;
    int n = (int)(q >> 11), k = (int)(q & 2047);
    int nb = n >> 6, gate = (n >> 4) & 3, u = n & 15;
    int r = gate * 1024 + nb * 16 + u;
    float v = (k < 1024) ? Wih1[(size_t)r * 1024 + k]
                         : Whh1[(size_t)r * 1024 + (k - 1024)];
    B1[q] = (_Float16)v;
  } else if (e < S0 + 2 * S1) {
    size_t q = e - S0 - S1;
    int n = (int)(q >> 11), k = (int)(q & 2047);
    int nb = n >> 6, gate = (n >> 4) & 3, u = n & 15;
    int r = gate * 1024 + nb * 16 + u;
    float v = (k < 1024) ? Wih2[(size_t)r * 1024 + k]
                         : Whh2[(size_t)r * 1024 + (k - 1024)];
    B2[q] = (_Float16)v;
  } else if (e < S0 + 2 * S1 + 40960) {
    int q = (int)(e - S0 - 2 * S1);
    int n = q / 10, k = q - n * 10;
    int nb = n >> 6, gate = (n >> 4) & 3, u = n & 15;
    int r = gate * 1024 + nb * 16 + u;
    W0p[q] = Wih0[(size_t)r * 10 + k];
  } else if (e < S0 + 2 * S1 + 40960 + 12288) {
    int q = (int)(e - S0 - 2 * S1 - 40960);
    int l = q >> 12, n = q & 4095;
    int nb = n >> 6, gate = (n >> 4) & 3, u = n & 15;
    int r = gate * 1024 + nb * 16 + u;
    const float* bi = (l == 0) ? bih0 : (l == 1) ? bih1 : bih2;
    const float* bh = (l == 0) ? bhh0 : (l == 1) ? bhh1 : bhh2;
    biasP[q] = bi[r] + bh[r];
  }
}

// ---------------------------------------------------------------------------
// Encoder wavefront kernel (unchanged): dispatch d = L0@t=d, L1@d-1, L2@d-2.
// ---------------------------------------------------------------------------
__global__ __launch_bounds__(256) void lstm_wave(
    int d,
    _Float16* __restrict__ h0p0, _Float16* __restrict__ h0p1,
    _Float16* __restrict__ h1p0, _Float16* __restrict__ h1p1,
    _Float16* __restrict__ h2p0, _Float16* __restrict__ h2p1,
    const _Float16* __restrict__ B0g, const _Float16* __restrict__ B1g,
    const _Float16* __restrict__ B2g,
    const float* __restrict__ biasP, const float* __restrict__ W0p,
    float* __restrict__ c0, float* __restrict__ c1, float* __restrict__ c2,
    const float* __restrict__ x, const int* __restrict__ xte,
    const float* __restrict__ e0, const float* __restrict__ e1,
    const float* __restrict__ e2, const float* __restrict__ e3)
{
  __shared__ __align__(16) char smem[32768];
  __shared__ float SmallIn[BM * SK];
  __shared__ float W0s[BN * 11];

  const int layer = blockIdx.y >> 2;
  const int mb = blockIdx.y & 3, nb = blockIdx.x;
  const int t = d - layer;
  if (t < 0 || t >= TSEQ) return;
  const int p = d & 1;

  const _Float16 *A1, *A2; _Float16* ho; const _Float16* Bm;
  const float* bias; float* cst; int Kdim;
  if (layer == 0) {
    A1 = p ? h0p1 : h0p0; A2 = A1;              ho = p ? h0p0 : h0p1;
    Bm = B0g; bias = biasP;        cst = c0; Kdim = 1024;
  } else if (layer == 1) {
    A1 = p ? h0p1 : h0p0; A2 = p ? h1p1 : h1p0; ho = p ? h1p0 : h1p1;
    Bm = B1g; bias = biasP + 4096; cst = c1; Kdim = 2048;
  } else {
    A1 = p ? h1p1 : h1p0; A2 = p ? h2p1 : h2p0; ho = p ? h2p0 : h2p1;
    Bm = B2g; bias = biasP + 8192; cst = c2; Kdim = 2048;
  }
  const int Mbase = mb * BM;
  const int tid = threadIdx.x;

  if (layer == 0 && tid < BM) {
    int Mg = Mbase + tid;
    float v[SK];
    const float* xp = x + ((size_t)Mg * TSEQ + t) * IND;
#pragma unroll
    for (int i = 0; i < IND; ++i) v[i] = xp[i];
    const int* ip = xte + ((size_t)Mg * TSEQ + t) * 4;
    int i0 = ip[0], i1 = ip[1], i2 = ip[2], i3 = ip[3];
#pragma unroll
    for (int dd = 0; dd < 3; ++dd)
      v[IND + dd] = e0[i0 * 3 + dd] + e1[i1 * 3 + dd] + e2[i2 * 3 + dd] + e3[i3 * 3 + dd];
#pragma unroll
    for (int i = 0; i < SK; ++i) SmallIn[tid * SK + i] = v[i];
    const float* wp = W0p + (size_t)(nb * BN + tid) * SK;
#pragma unroll
    for (int i = 0; i < SK; ++i) W0s[tid * 11 + i] = wp[i];
  }

  _Float16* As = (_Float16*)smem;
  _Float16* Bs = (_Float16*)(smem + 16384);

  const int w = tid >> 6, lane = tid & 63;
  const int quad = lane >> 4, l16 = lane & 15;
  const int dr = lane >> 4, ds = lane & 15;

  size_t a_goff[4], b_goff[4];
  int lds_off[4];
#pragma unroll
  for (int i = 0; i < 4; ++i) {
    int lrow = w * 16 + i * 4 + dr;
    int sg = ds ^ (i * 4 + dr);
    a_goff[i] = (size_t)(Mbase + lrow) * (HID * 2) + (size_t)sg * 16;
    b_goff[i] = (size_t)(nb * BN + lrow) * ((size_t)Kdim * 2) + (size_t)sg * 16;
    lds_off[i] = lrow * 256 + ds * 16;
  }

  f32x4 acc[4] = {};

  for (int kk = 0; kk < Kdim; kk += 128) {
    const char* Abase = (kk < 1024)
        ? ((const char*)A1 + (size_t)kk * 2)
        : ((const char*)A2 + (size_t)(kk - 1024) * 2);
    const char* Bbase = (const char*)Bm + (size_t)kk * 2;
#pragma unroll
    for (int i = 0; i < 4; ++i) {
      async_cp16<0>(Abase + a_goff[i], smem + lds_off[i]);
      async_cp16<0>(Bbase + b_goff[i], smem + 16384 + lds_off[i]);
    }
    __syncthreads();
#pragma unroll
    for (int ks = 0; ks < 4; ++ks) {
      int segq = (ks * 4 + quad) ^ l16;
      f16x8 bf = *reinterpret_cast<const f16x8*>(Bs + (w * 16 + l16) * 128 + segq * 8);
#pragma unroll
      for (int mt = 0; mt < 4; ++mt) {
        f16x8 af = *reinterpret_cast<const f16x8*>(As + (mt * 16 + l16) * 128 + segq * 8);
        acc[mt] = __builtin_amdgcn_mfma_f32_16x16x32_f16(af, bf, acc[mt], 0, 0, 0);
      }
    }
    __syncthreads();
  }

  float* Gs = (float*)smem;
#pragma unroll
  for (int mt = 0; mt < 4; ++mt) {
    int row = mt * 16 + quad * 4;
    int col = w * 16 + l16;
#pragma unroll
    for (int r = 0; r < 4; ++r)
      Gs[(row + r) * GSTR + col] = acc[mt][r];
  }
  __syncthreads();

#pragma unroll
  for (int i = 0; i < 4; ++i) {
    int m = (tid >> 4) + i * 16;
    int u = tid & 15;
    float gi = Gs[m * GSTR + u];
    float gf = Gs[m * GSTR + 16 + u];
    float gg = Gs[m * GSTR + 32 + u];
    float go = Gs[m * GSTR + 48 + u];
    int nbase = nb * BN;
    gi += bias[nbase + u];
    gf += bias[nbase + 16 + u];
    gg += bias[nbase + 32 + u];
    go += bias[nbase + 48 + u];
    if (layer == 0) {
#pragma unroll
      for (int k = 0; k < SK; ++k) {
        float sv = SmallIn[m * SK + k];
        gi += sv * W0s[u * 11 + k];
        gf += sv * W0s[(16 + u) * 11 + k];
        gg += sv * W0s[(32 + u) * 11 + k];
        go += sv * W0s[(48 + u) * 11 + k];
      }
    }
    size_t cidx = (size_t)(Mbase + m) * HID + (size_t)nb * 16 + u;
    float cold = cst[cidx];
    float cn = sigmoidf_fast(gf) * cold + sigmoidf_fast(gi) * tanhf_fast(gg);
    float hn = sigmoidf_fast(go) * tanhf_fast(cn);
    cst[cidx] = cn;
    ho[cidx] = (_Float16)hn;
  }
}

// ---------------------------------------------------------------------------
// Decoder phase kernel v8: one layer-phase per dispatch (v6's proven
// coherence model: plain cached ops, kernel-boundary visibility), but with
// the ENCODER's 64x64 tile geometry (A read 64x, B read 4x = 134 MB/deep
// phase vs v6's 201 MB) and R0's proven ring-4 depth-3 prefetch pipeline.
// Grid (64 nb, 4 mb) = 256 blocks, 154 KB LDS -> 1 block/CU; panel-sharers
// (same nb) are bids == nb (mod 8) -> same XCD (panel fetched once per XCD).
// MODE 1: L0 (K=1024, +small input). MODE 2: deep. MODE 3: deep + fused fc.
// ---------------------------------------------------------------------------
template<int KC, int MODE>
__global__ __launch_bounds__(256, 1) void dec_phase(
    const _Float16* __restrict__ A1g, const _Float16* __restrict__ A2g,
    _Float16* __restrict__ ho, const _Float16* __restrict__ Bm,
    const float* __restrict__ biasL, const float* __restrict__ W0p,
    float* __restrict__ cst, float* __restrict__ out,
    const int* __restrict__ yte,
    const float* __restrict__ e0, const float* __restrict__ e1,
    const float* __restrict__ e2, const float* __restrict__ e3,
    const float* __restrict__ fcW, const float* __restrict__ fcb, int s)
{
  __shared__ __align__(16) char smem[4 * 32768];   // ring-4: A 16KB + B 16KB
  __shared__ float Gs[BM * GSTR];                  // 17 KB
  __shared__ float SmallIn[BM * SK];
  __shared__ float W0s[BN * 11];

  const int tid = threadIdx.x;
  const int nb = blockIdx.x, mb = blockIdx.y;
  const int Mbase = mb * BM;

  if (MODE == 1 && tid < BM) {
    int Mg = Mbase + tid;
    float v[SK];
    const float* yp = out + (size_t)Mg * (PRED * OUTD) + s * OUTD;
#pragma unroll
    for (int i = 0; i < OUTD; ++i) v[i] = yp[i];   // plain loads: boundary-coherent
    const int* ip = yte + ((size_t)Mg * PRED + s) * 4;
    int i0 = ip[0], i1 = ip[1], i2 = ip[2], i3 = ip[3];
#pragma unroll
    for (int dd = 0; dd < 3; ++dd)
      v[IND + dd] = e0[i0 * 3 + dd] + e1[i1 * 3 + dd]
                  + e2[i2 * 3 + dd] + e3[i3 * 3 + dd];
#pragma unroll
    for (int i = 0; i < SK; ++i) SmallIn[tid * SK + i] = v[i];
    const float* wp = W0p + (size_t)(nb * BN + tid) * SK;
#pragma unroll
    for (int i = 0; i < SK; ++i) W0s[tid * 11 + i] = wp[i];
  }

  const int w = tid >> 6, lane = tid & 63;
  const int quad = lane >> 4, l16 = lane & 15;

  // encoder's proven staging map: thread stages 4 A-rows + 4 B-rows,
  // lds row = w*16 + i*4 + quad, source 16B-seg = l16 ^ (row&15)
  size_t a_goff[4], b_goff[4];
  int lds_off[4];
#pragma unroll
  for (int i = 0; i < 4; ++i) {
    int lrow = w * 16 + i * 4 + quad;
    int sg = l16 ^ (i * 4 + quad);
    a_goff[i] = (size_t)(Mbase + lrow) * 2048 + (size_t)sg * 16;
    b_goff[i] = (size_t)(nb * BN + lrow) * ((size_t)KC * 256) + (size_t)sg * 16;
    lds_off[i] = lrow * 256 + l16 * 16;
  }

#define PISSUE(c) do { \
    const char* Ab_ = (KC == 8 || (c) < 8) \
        ? ((const char*)A1g + (size_t)(c) * 256) \
        : ((const char*)A2g + (size_t)((c) - 8) * 256); \
    const char* Bb_ = (const char*)Bm + (size_t)(c) * 256; \
    char* L_ = smem + ((c) & 3) * 32768; \
    _Pragma("unroll") \
    for (int i_ = 0; i_ < 4; ++i_) { \
      async_cp16<0>(Ab_ + a_goff[i_], L_ + lds_off[i_]); \
      async_cp16<0>(Bb_ + b_goff[i_], L_ + 16384 + lds_off[i_]); \
    } } while (0)

  f32x4 acc[4] = {};
  PISSUE(0);
  PISSUE(1);
  PISSUE(2);
#pragma unroll
  for (int c = 0; c < KC; ++c) {
    if (c + 3 < KC)       { PISSUE(c + 3); WBAR(24); }
    else if (c + 3 == KC) { WBAR(16); }
    else if (c + 2 == KC) { WBAR(8); }
    else                  { WBAR(0); }
    const _Float16* As = (const _Float16*)(smem + (c & 3) * 32768);
    const _Float16* Bs = As + 8192;
#pragma unroll
    for (int ks = 0; ks < 4; ++ks) {
      int sq = (ks * 4 + quad) ^ l16;
      f16x8 bf = *reinterpret_cast<const f16x8*>(Bs + (w * 16 + l16) * 128 + sq * 8);
#pragma unroll
      for (int mt = 0; mt < 4; ++mt) {
        f16x8 af = *reinterpret_cast<const f16x8*>(As + (mt * 16 + l16) * 128 + sq * 8);
        acc[mt] = __builtin_amdgcn_mfma_f32_16x16x32_f16(af, bf, acc[mt], 0, 0, 0);
      }
    }
    BARO();   // ring-slot recycle guard
  }
#undef PISSUE

  // epilogue: gates transpose via LDS, pointwise, h/c plain stores
#pragma unroll
  for (int mt = 0; mt < 4; ++mt) {
    int row = mt * 16 + quad * 4;
    int col = w * 16 + l16;
#pragma unroll
    for (int r = 0; r < 4; ++r)
      Gs[(row + r) * GSTR + col] = acc[mt][r];
  }
  __syncthreads();

  const int u = tid & 15;
#pragma unroll
  for (int i = 0; i < 4; ++i) {
    int m = (tid >> 4) + i * 16;
    int nbase = nb * BN;
    float gi = Gs[m * GSTR + u]      + biasL[nbase + u];
    float gf = Gs[m * GSTR + 16 + u] + biasL[nbase + 16 + u];
    float gg = Gs[m * GSTR + 32 + u] + biasL[nbase + 32 + u];
    float go = Gs[m * GSTR + 48 + u] + biasL[nbase + 48 + u];
    if (MODE == 1) {
#pragma unroll
      for (int k = 0; k < SK; ++k) {
        float sv = SmallIn[m * SK + k];
        gi += sv * W0s[u * 11 + k];
        gf += sv * W0s[(16 + u) * 11 + k];
        gg += sv * W0s[(32 + u) * 11 + k];
        go += sv * W0s[(48 + u) * 11 + k];
      }
    }
    size_t cidx = (size_t)(Mbase + m) * HID + (size_t)nb * 16 + u;
    float cold = cst[cidx];
    float cn = sigmoidf_fast(gf) * cold + sigmoidf_fast(gi) * tanhf_fast(gg);
    float hn = sigmoidf_fast(go) * tanhf_fast(cn);
    cst[cidx] = cn;
    ho[cidx] = (_Float16)hn;
    if (MODE == 3) {
#pragma unroll
      for (int o = 0; o < OUTD; ++o) {
        float r = hn * fcW[(size_t)o * HID + nb * 16 + u];
        r += __shfl_xor(r, 1, 16);
        r += __shfl_xor(r, 2, 16);
        r += __shfl_xor(r, 4, 16);
        r += __shfl_xor(r, 8, 16);
        if (u == 0)
          atomicAdd(&out[(size_t)(Mbase + m) * (PRED * OUTD) + (s + 1) * OUTD + o],
                    r + ((nb == 0) ? fcb[o] : 0.0f));
      }
    }
  }
}

// ---------------------------------------------------------------------------
// Standalone FC head for y0 only: y = h2 @ fcW^T + fcb -> out[:,0,:].
// ---------------------------------------------------------------------------
__global__ __launch_bounds__(256) void fc_kernel(
    const _Float16* __restrict__ h2, const float* __restrict__ fcW,
    const float* __restrict__ fcb, float* __restrict__ out)
{
  int wv = threadIdx.x >> 6, lane = threadIdx.x & 63;
  int row = blockIdx.x * 4 + wv;
  const _Float16* hp = h2 + (size_t)row * HID + lane * 16;
  float hv[16];
#pragma unroll
  for (int i = 0; i < 16; ++i) hv[i] = (float)hp[i];
  float acc[OUTD];
#pragma unroll
  for (int o = 0; o < OUTD; ++o) {
    const float* wp = fcW + (size_t)o * HID + lane * 16;
    float a = 0.f;
#pragma unroll
    for (int i = 0; i < 16; ++i) a += hv[i] * wp[i];
    acc[o] = a;
  }
#pragma unroll
  for (int o = 0; o < OUTD; ++o)
#pragma unroll
    for (int off = 32; off >= 1; off >>= 1)
      acc[o] += __shfl_xor(acc[o], off, 64);
  if (lane == 0) {
#pragma unroll
    for (int o = 0; o < OUTD; ++o)
      out[(size_t)row * (PRED * OUTD) + o] = acc[o] + fcb[o];
  }
}

// ---------------------------------------------------------------------------
// Workspace layout (bytes):
//   B0 @0 (8 MB) | B1 @8388608 (16 MB) | B2 @25165824 (16 MB)
//   W0p @41943040 | biasP @42106880
//   h par0 @42156032 (1.5 MB) + c @43728896 (3 MB)  } one memset
//   h par1 @46874624 (1.5 MB)                        } second memset
// ---------------------------------------------------------------------------
extern "C" void kernel_launch(void* const* d_in, const int* in_sizes, int n_in,
                              void* d_out, int out_size, void* d_ws, size_t ws_size,
                              hipStream_t stream) {
  const float* x   = (const float*)d_in[0];
  const int*   xte = (const int*)d_in[2];
  const int*   yte = (const int*)d_in[3];
  const float* e0  = (const float*)d_in[4];
  const float* e1  = (const float*)d_in[5];
  const float* e2  = (const float*)d_in[6];
  const float* e3  = (const float*)d_in[7];
  const float* Wih0 = (const float*)d_in[8];
  const float* Whh0 = (const float*)d_in[9];
  const float* bih0 = (const float*)d_in[10];
  const float* bhh0 = (const float*)d_in[11];
  const float* Wih1 = (const float*)d_in[12];
  const float* Whh1 = (const float*)d_in[13];
  const float* bih1 = (const float*)d_in[14];
  const float* bhh1 = (const float*)d_in[15];
  const float* Wih2 = (const float*)d_in[16];
  const float* Whh2 = (const float*)d_in[17];
  const float* bih2 = (const float*)d_in[18];
  const float* bhh2 = (const float*)d_in[19];
  const float* fcW = (const float*)d_in[20];
  const float* fcb = (const float*)d_in[21];
  float* out = (float*)d_out;

  char* ws = (char*)d_ws;
  _Float16* B0   = (_Float16*)(ws);
  _Float16* B1   = (_Float16*)(ws + 8388608);
  _Float16* B2   = (_Float16*)(ws + 25165824);
  float*    W0p  = (float*)(ws + 41943040);
  float*    biasP= (float*)(ws + 42106880);
  char*     hp0  = ws + 42156032;
  float*    cbuf = (float*)(ws + 43728896);
  char*     hp1  = ws + 46874624;

  hipMemsetAsync(out, 0, (size_t)out_size * 4, stream);
  hipMemsetAsync(hp0, 0, 4718592, stream);
  hipMemsetAsync(hp1, 0, 1572864, stream);

  prep_kernel<<<82128, 256, 0, stream>>>(Wih0, Whh0, bih0, bhh0,
                                         Wih1, Whh1, bih1, bhh1,
                                         Wih2, Whh2, bih2, bhh2,
                                         B0, B1, B2, W0p, biasP);

  auto hb = [&](int l, int par) -> _Float16* {
    return (_Float16*)((par ? hp1 : hp0) + (size_t)l * 524288);
  };
  float* cl[3] = {cbuf, cbuf + 262144, cbuf + 524288};

  // encoder: wavefront over (layer, t) diagonals
  for (int d = 0; d < TSEQ + 2; ++d) {
    lstm_wave<<<dim3(64, 12), 256, 0, stream>>>(
        d, hb(0,0), hb(0,1), hb(1,0), hb(1,1), hb(2,0), hb(2,1),
        B0, B1, B2, biasP, W0p, cl[0], cl[1], cl[2],
        x, xte, e0, e1, e2, e3);
  }

  // handoff parities: h0@127 -> par0, h1@127 -> par1, h2@127 -> par0
  fc_kernel<<<64, 256, 0, stream>>>(hb(2,0), fcW, fcb, out);   // y0

  // decoder: 95 steps x 3 layer-phase dispatches, kernel-boundary coherence
  int p0 = 0, p1 = 1, p2 = 0;
  const dim3 dgrid(64, 4);
  for (int s = 0; s < PRED - 1; ++s) {
    dec_phase<8, 1><<<dgrid, 256, 0, stream>>>(
        hb(0, p0), hb(0, p0), hb(0, 1 - p0), B0,
        biasP, W0p, cl[0], out, yte, e0, e1, e2, e3, fcW, fcb, s);
    dec_phase<16, 2><<<dgrid, 256, 0, stream>>>(
        hb(0, 1 - p0), hb(1, p1), hb(1, 1 - p1), B1,
        biasP + 4096, W0p, cl[1], out, yte, e0, e1, e2, e3, fcW, fcb, s);
    dec_phase<16, 3><<<dgrid, 256, 0, stream>>>(
        hb(1, 1 - p1), hb(2, p2), hb(2, 1 - p2), B2,
        biasP + 8192, W0p, cl[2], out, yte, e0, e1, e2, e3, fcW, fcb, s);
    p0 ^= 1; p1 ^= 1; p2 ^= 1;
  }
}

// Round 8
// 7783.411 us; speedup vs baseline: 1.1162x; 1.1162x over previous
//
#include <hip/hip_runtime.h>

#define HID   1024
#define BATCH 256
#define TSEQ  128
#define PRED  96
#define IND   7
#define OUTD  7
#define SK    10   // small input dim: 7 features + 3 time-encode dims

typedef __attribute__((ext_vector_type(8))) _Float16 f16x8;
typedef __attribute__((ext_vector_type(4))) float    f32x4;

// encoder tile (unchanged, proven)
#define BM   64
#define BN   64
#define GSTR 68    // gates LDS stride (floats), <=2-way bank aliasing (free)

__device__ __forceinline__ float sigmoidf_fast(float x) {
  return 1.0f / (1.0f + __expf(-x));
}
__device__ __forceinline__ float tanhf_fast(float x) {
  float ax = fabsf(x);
  float e  = __expf(-2.0f * ax);
  float r  = (1.0f - e) / (1.0f + e);
  return copysignf(r, x);
}

template<int AUX>
__device__ __forceinline__ void async_cp16(const void* g, void* l) {
  __builtin_amdgcn_global_load_lds(
      (const __attribute__((address_space(1))) void*)g,
      (__attribute__((address_space(3))) void*)l, 16, 0, AUX);
}

// fine-grained wait + barrier (pipeline)
#define WBAR(N) asm volatile("s_waitcnt vmcnt(" #N ")\n\ts_barrier" ::: "memory")
#define BARO()  asm volatile("s_barrier" ::: "memory")

// ---------------------------------------------------------------------------
// Weight prep: fp16 B [n][k], n = grp*64 + gate*16 + u <-> r = gate*1024+grp*16+u
// ---------------------------------------------------------------------------
__global__ __launch_bounds__(256) void prep_kernel(
    const float* __restrict__ Wih0, const float* __restrict__ Whh0,
    const float* __restrict__ bih0, const float* __restrict__ bhh0,
    const float* __restrict__ Wih1, const float* __restrict__ Whh1,
    const float* __restrict__ bih1, const float* __restrict__ bhh1,
    const float* __restrict__ Wih2, const float* __restrict__ Whh2,
    const float* __restrict__ bih2, const float* __restrict__ bhh2,
    _Float16* __restrict__ B0, _Float16* __restrict__ B1, _Float16* __restrict__ B2,
    float* __restrict__ W0p, float* __restrict__ biasP)
{
  size_t e = (size_t)blockIdx.x * 256 + threadIdx.x;
  const size_t S0 = (size_t)4096 * 1024;
  const size_t S1 = (size_t)4096 * 2048;
  if (e < S0) {
    int n = (int)(e >> 10), k = (int)(e & 1023);
    int nb = n >> 6, gate = (n >> 4) & 3, u = n & 15;
    int r = gate * 1024 + nb * 16 + u;
    B0[e] = (_Float16)Whh0[(size_t)r * 1024 + k];
  } else if (e < S0 + S1) {
    size_t q = e - S0;
    int n = (int)(q >> 11), k = (int)(q & 2047);
    int nb = n >> 6, gate = (n >> 4) & 3, u = n & 15;
    int r = gate * 1024 + nb * 16 + u;
    float v = (k < 1024) ? Wih1[(size_t)r * 1024 + k]
                         : Whh1[(size_t)r * 1024 + (k - 1024)];
    B1[q] = (_Float16)v;
  } else if (e < S0 + 2 * S1) {
    size_t q = e - S0 - S1;
    int n = (int)(q >> 11), k = (int)(q & 2047);
    int nb = n >> 6, gate = (n >> 4) & 3, u = n & 15;
    int r = gate * 1024 + nb * 16 + u;
    float v = (k < 1024) ? Wih2[(size_t)r * 1024 + k]
                         : Whh2[(size_t)r * 1024 + (k - 1024)];
    B2[q] = (_Float16)v;
  } else if (e < S0 + 2 * S1 + 40960) {
    int q = (int)(e - S0 - 2 * S1);
    int n = q / 10, k = q - n * 10;
    int nb = n >> 6, gate = (n >> 4) & 3, u = n & 15;
    int r = gate * 1024 + nb * 16 + u;
    W0p[q] = Wih0[(size_t)r * 10 + k];
  } else if (e < S0 + 2 * S1 + 40960 + 12288) {
    int q = (int)(e - S0 - 2 * S1 - 40960);
    int l = q >> 12, n = q & 4095;
    int nb = n >> 6, gate = (n >> 4) & 3, u = n & 15;
    int r = gate * 1024 + nb * 16 + u;
    const float* bi = (l == 0) ? bih0 : (l == 1) ? bih1 : bih2;
    const float* bh = (l == 0) ? bhh0 : (l == 1) ? bhh1 : bhh2;
    biasP[q] = bi[r] + bh[r];
  }
}

// ---------------------------------------------------------------------------
// Encoder wavefront kernel (unchanged): dispatch d = L0@t=d, L1@d-1, L2@d-2.
// ---------------------------------------------------------------------------
__global__ __launch_bounds__(256) void lstm_wave(
    int d,
    _Float16* __restrict__ h0p0, _Float16* __restrict__ h0p1,
    _Float16* __restrict__ h1p0, _Float16* __restrict__ h1p1,
    _Float16* __restrict__ h2p0, _Float16* __restrict__ h2p1,
    const _Float16* __restrict__ B0g, const _Float16* __restrict__ B1g,
    const _Float16* __restrict__ B2g,
    const float* __restrict__ biasP, const float* __restrict__ W0p,
    float* __restrict__ c0, float* __restrict__ c1, float* __restrict__ c2,
    const float* __restrict__ x, const int* __restrict__ xte,
    const float* __restrict__ e0, const float* __restrict__ e1,
    const float* __restrict__ e2, const float* __restrict__ e3)
{
  __shared__ __align__(16) char smem[32768];
  __shared__ float SmallIn[BM * SK];
  __shared__ float W0s[BN * 11];

  const int layer = blockIdx.y >> 2;
  const int mb = blockIdx.y & 3, nb = blockIdx.x;
  const int t = d - layer;
  if (t < 0 || t >= TSEQ) return;
  const int p = d & 1;

  const _Float16 *A1, *A2; _Float16* ho; const _Float16* Bm;
  const float* bias; float* cst; int Kdim;
  if (layer == 0) {
    A1 = p ? h0p1 : h0p0; A2 = A1;              ho = p ? h0p0 : h0p1;
    Bm = B0g; bias = biasP;        cst = c0; Kdim = 1024;
  } else if (layer == 1) {
    A1 = p ? h0p1 : h0p0; A2 = p ? h1p1 : h1p0; ho = p ? h1p0 : h1p1;
    Bm = B1g; bias = biasP + 4096; cst = c1; Kdim = 2048;
  } else {
    A1 = p ? h1p1 : h1p0; A2 = p ? h2p1 : h2p0; ho = p ? h2p0 : h2p1;
    Bm = B2g; bias = biasP + 8192; cst = c2; Kdim = 2048;
  }
  const int Mbase = mb * BM;
  const int tid = threadIdx.x;

  if (layer == 0 && tid < BM) {
    int Mg = Mbase + tid;
    float v[SK];
    const float* xp = x + ((size_t)Mg * TSEQ + t) * IND;
#pragma unroll
    for (int i = 0; i < IND; ++i) v[i] = xp[i];
    const int* ip = xte + ((size_t)Mg * TSEQ + t) * 4;
    int i0 = ip[0], i1 = ip[1], i2 = ip[2], i3 = ip[3];
#pragma unroll
    for (int dd = 0; dd < 3; ++dd)
      v[IND + dd] = e0[i0 * 3 + dd] + e1[i1 * 3 + dd] + e2[i2 * 3 + dd] + e3[i3 * 3 + dd];
#pragma unroll
    for (int i = 0; i < SK; ++i) SmallIn[tid * SK + i] = v[i];
    const float* wp = W0p + (size_t)(nb * BN + tid) * SK;
#pragma unroll
    for (int i = 0; i < SK; ++i) W0s[tid * 11 + i] = wp[i];
  }

  _Float16* As = (_Float16*)smem;
  _Float16* Bs = (_Float16*)(smem + 16384);

  const int w = tid >> 6, lane = tid & 63;
  const int quad = lane >> 4, l16 = lane & 15;
  const int dr = lane >> 4, ds = lane & 15;

  size_t a_goff[4], b_goff[4];
  int lds_off[4];
#pragma unroll
  for (int i = 0; i < 4; ++i) {
    int lrow = w * 16 + i * 4 + dr;
    int sg = ds ^ (i * 4 + dr);
    a_goff[i] = (size_t)(Mbase + lrow) * (HID * 2) + (size_t)sg * 16;
    b_goff[i] = (size_t)(nb * BN + lrow) * ((size_t)Kdim * 2) + (size_t)sg * 16;
    lds_off[i] = lrow * 256 + ds * 16;
  }

  f32x4 acc[4] = {};

  for (int kk = 0; kk < Kdim; kk += 128) {
    const char* Abase = (kk < 1024)
        ? ((const char*)A1 + (size_t)kk * 2)
        : ((const char*)A2 + (size_t)(kk - 1024) * 2);
    const char* Bbase = (const char*)Bm + (size_t)kk * 2;
#pragma unroll
    for (int i = 0; i < 4; ++i) {
      async_cp16<0>(Abase + a_goff[i], smem + lds_off[i]);
      async_cp16<0>(Bbase + b_goff[i], smem + 16384 + lds_off[i]);
    }
    __syncthreads();
#pragma unroll
    for (int ks = 0; ks < 4; ++ks) {
      int segq = (ks * 4 + quad) ^ l16;
      f16x8 bf = *reinterpret_cast<const f16x8*>(Bs + (w * 16 + l16) * 128 + segq * 8);
#pragma unroll
      for (int mt = 0; mt < 4; ++mt) {
        f16x8 af = *reinterpret_cast<const f16x8*>(As + (mt * 16 + l16) * 128 + segq * 8);
        acc[mt] = __builtin_amdgcn_mfma_f32_16x16x32_f16(af, bf, acc[mt], 0, 0, 0);
      }
    }
    __syncthreads();
  }

  float* Gs = (float*)smem;
#pragma unroll
  for (int mt = 0; mt < 4; ++mt) {
    int row = mt * 16 + quad * 4;
    int col = w * 16 + l16;
#pragma unroll
    for (int r = 0; r < 4; ++r)
      Gs[(row + r) * GSTR + col] = acc[mt][r];
  }
  __syncthreads();

#pragma unroll
  for (int i = 0; i < 4; ++i) {
    int m = (tid >> 4) + i * 16;
    int u = tid & 15;
    float gi = Gs[m * GSTR + u];
    float gf = Gs[m * GSTR + 16 + u];
    float gg = Gs[m * GSTR + 32 + u];
    float go = Gs[m * GSTR + 48 + u];
    int nbase = nb * BN;
    gi += bias[nbase + u];
    gf += bias[nbase + 16 + u];
    gg += bias[nbase + 32 + u];
    go += bias[nbase + 48 + u];
    if (layer == 0) {
#pragma unroll
      for (int k = 0; k < SK; ++k) {
        float sv = SmallIn[m * SK + k];
        gi += sv * W0s[u * 11 + k];
        gf += sv * W0s[(16 + u) * 11 + k];
        gg += sv * W0s[(32 + u) * 11 + k];
        go += sv * W0s[(48 + u) * 11 + k];
      }
    }
    size_t cidx = (size_t)(Mbase + m) * HID + (size_t)nb * 16 + u;
    float cold = cst[cidx];
    float cn = sigmoidf_fast(gf) * cold + sigmoidf_fast(gi) * tanhf_fast(gg);
    float hn = sigmoidf_fast(go) * tanhf_fast(cn);
    cst[cidx] = cn;
    ho[cidx] = (_Float16)hn;
  }
}

// ---------------------------------------------------------------------------
// Decoder phase kernel v9 = v6 (best-known: 32x64 tile, 512 blocks, 2/CU,
// kernel-boundary coherence) with ONE change: ring-2 depth-1 -> ring-3
// depth-2 prefetch (WBAR(12)), gates buffer aliased into the drained ring
// so LDS stays at 77.8KB -> still 2 blocks/CU.
// Grid (64 nb, 8 mb) = 512 blocks; the 8 mb-sharers of a B-panel have
// bid % 8 == nb % 8 -> same XCD under round-robin (panel L2-local).
// MODE 1: L0 (K=1024, +small input). MODE 2: deep. MODE 3: deep + fused fc.
// ---------------------------------------------------------------------------
template<int KC, int MODE>
__global__ __launch_bounds__(256, 2) void dec_phase(
    const _Float16* __restrict__ A1g, const _Float16* __restrict__ A2g,
    _Float16* __restrict__ ho, const _Float16* __restrict__ Bm,
    const float* __restrict__ biasL, const float* __restrict__ W0p,
    float* __restrict__ cst, float* __restrict__ out,
    const int* __restrict__ yte,
    const float* __restrict__ e0, const float* __restrict__ e1,
    const float* __restrict__ e2, const float* __restrict__ e3,
    const float* __restrict__ fcW, const float* __restrict__ fcb, int s)
{
  __shared__ __align__(16) char smem[3 * 24576];   // ring-3: A 8KB + B 16KB
  __shared__ float SmallIn[32 * SK];
  __shared__ float W0s[64 * 11];
  // gates buffer aliases the ring (all staging drained before epilogue)
  float* Gs = (float*)smem;                        // 32*GSTR*4 = 8.7KB < slot

  const int tid = threadIdx.x;
  const int nb = blockIdx.x, mb = blockIdx.y;
  const int Mbase = mb * 32;

  if (MODE == 1) {
    if (tid < 32) {
      int Mg = Mbase + tid;
      float v[SK];
      const float* yp = out + (size_t)Mg * (PRED * OUTD) + s * OUTD;
#pragma unroll
      for (int i = 0; i < OUTD; ++i) v[i] = yp[i];   // plain loads: boundary-coherent
      const int* ip = yte + ((size_t)Mg * PRED + s) * 4;
      int i0 = ip[0], i1 = ip[1], i2 = ip[2], i3 = ip[3];
#pragma unroll
      for (int dd = 0; dd < 3; ++dd)
        v[IND + dd] = e0[i0 * 3 + dd] + e1[i1 * 3 + dd]
                    + e2[i2 * 3 + dd] + e3[i3 * 3 + dd];
#pragma unroll
      for (int i = 0; i < SK; ++i) SmallIn[tid * SK + i] = v[i];
    }
    if (tid < 64) {
      const float* wp = W0p + (size_t)(nb * 64 + tid) * SK;
#pragma unroll
      for (int i = 0; i < SK; ++i) W0s[tid * 11 + i] = wp[i];
    }
  }

  const int w = tid >> 6, lane = tid & 63;
  const int quad = lane >> 4, l16 = lane & 15;

  // staging offsets: slot j = op*256+tid -> row = j>>4, lds-seg = j&15,
  // source seg = (j&15) ^ (row&15)  (16-seg XOR swizzle; h row stride 2048B)
  int a_src[2], a_dst[2], b_src[4], b_dst[4];
#pragma unroll
  for (int op = 0; op < 2; ++op) {
    int j = op * 256 + tid, row = j >> 4, seg = j & 15;
    a_src[op] = (Mbase + row) * 2048 + ((seg ^ (row & 15)) * 16);
    a_dst[op] = row * 256 + seg * 16;
  }
#pragma unroll
  for (int op = 0; op < 4; ++op) {
    int j = op * 256 + tid, row = j >> 4, seg = j & 15;
    b_src[op] = (nb * 64 + row) * (KC * 256) + ((seg ^ (row & 15)) * 16);
    b_dst[op] = 8192 + row * 256 + seg * 16;
  }

#define PISSUE(c) do { \
    const char* Ab_ = (KC == 8 || (c) < 8) \
        ? ((const char*)A1g + (size_t)(c) * 256) \
        : ((const char*)A2g + (size_t)((c) - 8) * 256); \
    const char* Bb_ = (const char*)Bm + (size_t)(c) * 256; \
    char* L_ = smem + ((c) % 3) * 24576; \
    _Pragma("unroll") \
    for (int i_ = 0; i_ < 2; ++i_) async_cp16<0>(Ab_ + a_src[i_], L_ + a_dst[i_]); \
    _Pragma("unroll") \
    for (int i_ = 0; i_ < 4; ++i_) async_cp16<0>(Bb_ + b_src[i_], L_ + b_dst[i_]); \
  } while (0)

  f32x4 acc[2] = {};
  PISSUE(0);
  PISSUE(1);
#pragma unroll
  for (int c = 0; c < KC; ++c) {
    if (c + 2 < KC)       { PISSUE(c + 2); WBAR(12); }  // 2 chunks in flight
    else if (c + 2 == KC) { WBAR(6); }
    else                  { WBAR(0); }
    const _Float16* As = (const _Float16*)(smem + (c % 3) * 24576);
    const _Float16* Bs = As + 4096;
#pragma unroll
    for (int ks = 0; ks < 4; ++ks) {
      int sq = (ks * 4 + quad) ^ l16;
      f16x8 bf = *reinterpret_cast<const f16x8*>(Bs + (w * 16 + l16) * 128 + sq * 8);
#pragma unroll
      for (int mt = 0; mt < 2; ++mt) {
        f16x8 af = *reinterpret_cast<const f16x8*>(As + (mt * 16 + l16) * 128 + sq * 8);
        acc[mt] = __builtin_amdgcn_mfma_f32_16x16x32_f16(af, bf, acc[mt], 0, 0, 0);
      }
    }
    BARO();   // ring-slot recycle guard
  }
#undef PISSUE

  // epilogue: gates transpose via LDS (ring fully drained -> Gs alias safe),
  // pointwise, h/c plain stores
#pragma unroll
  for (int mt = 0; mt < 2; ++mt) {
    int row = mt * 16 + quad * 4;
    int col = w * 16 + l16;
#pragma unroll
    for (int r = 0; r < 4; ++r)
      Gs[(row + r) * GSTR + col] = acc[mt][r];
  }
  __syncthreads();

  const int u = tid & 15;
#pragma unroll
  for (int i = 0; i < 2; ++i) {
    int m = (tid >> 4) + i * 16;
    int nbase = nb * 64;
    float gi = Gs[m * GSTR + u]      + biasL[nbase + u];
    float gf = Gs[m * GSTR + 16 + u] + biasL[nbase + 16 + u];
    float gg = Gs[m * GSTR + 32 + u] + biasL[nbase + 32 + u];
    float go = Gs[m * GSTR + 48 + u] + biasL[nbase + 48 + u];
    if (MODE == 1) {
#pragma unroll
      for (int k = 0; k < SK; ++k) {
        float sv = SmallIn[m * SK + k];
        gi += sv * W0s[u * 11 + k];
        gf += sv * W0s[(16 + u) * 11 + k];
        gg += sv * W0s[(32 + u) * 11 + k];
        go += sv * W0s[(48 + u) * 11 + k];
      }
    }
    size_t cidx = (size_t)(Mbase + m) * HID + (size_t)nb * 16 + u;
    float cold = cst[cidx];
    float cn = sigmoidf_fast(gf) * cold + sigmoidf_fast(gi) * tanhf_fast(gg);
    float hn = sigmoidf_fast(go) * tanhf_fast(cn);
    cst[cidx] = cn;
    ho[cidx] = (_Float16)hn;
    if (MODE == 3) {
#pragma unroll
      for (int o = 0; o < OUTD; ++o) {
        float r = hn * fcW[(size_t)o * HID + nb * 16 + u];
        r += __shfl_xor(r, 1, 16);
        r += __shfl_xor(r, 2, 16);
        r += __shfl_xor(r, 4, 16);
        r += __shfl_xor(r, 8, 16);
        if (u == 0)
          atomicAdd(&out[(size_t)(Mbase + m) * (PRED * OUTD) + (s + 1) * OUTD + o],
                    r + ((nb == 0) ? fcb[o] : 0.0f));
      }
    }
  }
}

// ---------------------------------------------------------------------------
// Standalone FC head for y0 only: y = h2 @ fcW^T + fcb -> out[:,0,:].
// ---------------------------------------------------------------------------
__global__ __launch_bounds__(256) void fc_kernel(
    const _Float16* __restrict__ h2, const float* __restrict__ fcW,
    const float* __restrict__ fcb, float* __restrict__ out)
{
  int wv = threadIdx.x >> 6, lane = threadIdx.x & 63;
  int row = blockIdx.x * 4 + wv;
  const _Float16* hp = h2 + (size_t)row * HID + lane * 16;
  float hv[16];
#pragma unroll
  for (int i = 0; i < 16; ++i) hv[i] = (float)hp[i];
  float acc[OUTD];
#pragma unroll
  for (int o = 0; o < OUTD; ++o) {
    const float* wp = fcW + (size_t)o * HID + lane * 16;
    float a = 0.f;
#pragma unroll
    for (int i = 0; i < 16; ++i) a += hv[i] * wp[i];
    acc[o] = a;
  }
#pragma unroll
  for (int o = 0; o < OUTD; ++o)
#pragma unroll
    for (int off = 32; off >= 1; off >>= 1)
      acc[o] += __shfl_xor(acc[o], off, 64);
  if (lane == 0) {
#pragma unroll
    for (int o = 0; o < OUTD; ++o)
      out[(size_t)row * (PRED * OUTD) + o] = acc[o] + fcb[o];
  }
}

// ---------------------------------------------------------------------------
// Workspace layout (bytes):
//   B0 @0 (8 MB) | B1 @8388608 (16 MB) | B2 @25165824 (16 MB)
//   W0p @41943040 | biasP @42106880
//   h par0 @42156032 (1.5 MB) + c @43728896 (3 MB)  } one memset
//   h par1 @46874624 (1.5 MB)                        } second memset
// ---------------------------------------------------------------------------
extern "C" void kernel_launch(void* const* d_in, const int* in_sizes, int n_in,
                              void* d_out, int out_size, void* d_ws, size_t ws_size,
                              hipStream_t stream) {
  const float* x   = (const float*)d_in[0];
  const int*   xte = (const int*)d_in[2];
  const int*   yte = (const int*)d_in[3];
  const float* e0  = (const float*)d_in[4];
  const float* e1  = (const float*)d_in[5];
  const float* e2  = (const float*)d_in[6];
  const float* e3  = (const float*)d_in[7];
  const float* Wih0 = (const float*)d_in[8];
  const float* Whh0 = (const float*)d_in[9];
  const float* bih0 = (const float*)d_in[10];
  const float* bhh0 = (const float*)d_in[11];
  const float* Wih1 = (const float*)d_in[12];
  const float* Whh1 = (const float*)d_in[13];
  const float* bih1 = (const float*)d_in[14];
  const float* bhh1 = (const float*)d_in[15];
  const float* Wih2 = (const float*)d_in[16];
  const float* Whh2 = (const float*)d_in[17];
  const float* bih2 = (const float*)d_in[18];
  const float* bhh2 = (const float*)d_in[19];
  const float* fcW = (const float*)d_in[20];
  const float* fcb = (const float*)d_in[21];
  float* out = (float*)d_out;

  char* ws = (char*)d_ws;
  _Float16* B0   = (_Float16*)(ws);
  _Float16* B1   = (_Float16*)(ws + 8388608);
  _Float16* B2   = (_Float16*)(ws + 25165824);
  float*    W0p  = (float*)(ws + 41943040);
  float*    biasP= (float*)(ws + 42106880);
  char*     hp0  = ws + 42156032;
  float*    cbuf = (float*)(ws + 43728896);
  char*     hp1  = ws + 46874624;

  hipMemsetAsync(out, 0, (size_t)out_size * 4, stream);
  hipMemsetAsync(hp0, 0, 4718592, stream);
  hipMemsetAsync(hp1, 0, 1572864, stream);

  prep_kernel<<<82128, 256, 0, stream>>>(Wih0, Whh0, bih0, bhh0,
                                         Wih1, Whh1, bih1, bhh1,
                                         Wih2, Whh2, bih2, bhh2,
                                         B0, B1, B2, W0p, biasP);

  auto hb = [&](int l, int par) -> _Float16* {
    return (_Float16*)((par ? hp1 : hp0) + (size_t)l * 524288);
  };
  float* cl[3] = {cbuf, cbuf + 262144, cbuf + 524288};

  // encoder: wavefront over (layer, t) diagonals
  for (int d = 0; d < TSEQ + 2; ++d) {
    lstm_wave<<<dim3(64, 12), 256, 0, stream>>>(
        d, hb(0,0), hb(0,1), hb(1,0), hb(1,1), hb(2,0), hb(2,1),
        B0, B1, B2, biasP, W0p, cl[0], cl[1], cl[2],
        x, xte, e0, e1, e2, e3);
  }

  // handoff parities: h0@127 -> par0, h1@127 -> par1, h2@127 -> par0
  fc_kernel<<<64, 256, 0, stream>>>(hb(2,0), fcW, fcb, out);   // y0

  // decoder: 95 steps x 3 layer-phase dispatches, kernel-boundary coherence
  int p0 = 0, p1 = 1, p2 = 0;
  const dim3 dgrid(64, 8);
  for (int s = 0; s < PRED - 1; ++s) {
    dec_phase<8, 1><<<dgrid, 256, 0, stream>>>(
        hb(0, p0), hb(0, p0), hb(0, 1 - p0), B0,
        biasP, W0p, cl[0], out, yte, e0, e1, e2, e3, fcW, fcb, s);
    dec_phase<16, 2><<<dgrid, 256, 0, stream>>>(
        hb(0, 1 - p0), hb(1, p1), hb(1, 1 - p1), B1,
        biasP + 4096, W0p, cl[1], out, yte, e0, e1, e2, e3, fcW, fcb, s);
    dec_phase<16, 3><<<dgrid, 256, 0, stream>>>(
        hb(1, 1 - p1), hb(2, p2), hb(2, 1 - p2), B2,
        biasP + 8192, W0p, cl[2], out, yte, e0, e1, e2, e3, fcW, fcb, s);
    p0 ^= 1; p1 ^= 1; p2 ^= 1;
  }
}

// Round 9
// 7528.195 us; speedup vs baseline: 1.1541x; 1.0339x over previous
//
#include <hip/hip_runtime.h>

#define HID   1024
#define BATCH 256
#define TSEQ  128
#define PRED  96
#define IND   7
#define OUTD  7
#define SK    10   // small input dim: 7 features + 3 time-encode dims

typedef __attribute__((ext_vector_type(8))) _Float16 f16x8;
typedef __attribute__((ext_vector_type(4))) float    f32x4;

// encoder tile (unchanged, proven)
#define BM   64
#define BN   64
#define GSTR 68    // gates LDS stride (floats), <=2-way bank aliasing (free)

__device__ __forceinline__ float sigmoidf_fast(float x) {
  return 1.0f / (1.0f + __expf(-x));
}
__device__ __forceinline__ float tanhf_fast(float x) {
  float ax = fabsf(x);
  float e  = __expf(-2.0f * ax);
  float r  = (1.0f - e) / (1.0f + e);
  return copysignf(r, x);
}

template<int AUX>
__device__ __forceinline__ void async_cp16(const void* g, void* l) {
  __builtin_amdgcn_global_load_lds(
      (const __attribute__((address_space(1))) void*)g,
      (__attribute__((address_space(3))) void*)l, 16, 0, AUX);
}

// fine-grained wait + barrier (pipeline)
#define WBAR(N) asm volatile("s_waitcnt vmcnt(" #N ")\n\ts_barrier" ::: "memory")
#define BARO()  asm volatile("s_barrier" ::: "memory")

// ---------------------------------------------------------------------------
// Weight prep: fp16 B [n][k], n = grp*64 + gate*16 + u <-> r = gate*1024+grp*16+u
// ---------------------------------------------------------------------------
__global__ __launch_bounds__(256) void prep_kernel(
    const float* __restrict__ Wih0, const float* __restrict__ Whh0,
    const float* __restrict__ bih0, const float* __restrict__ bhh0,
    const float* __restrict__ Wih1, const float* __restrict__ Whh1,
    const float* __restrict__ bih1, const float* __restrict__ bhh1,
    const float* __restrict__ Wih2, const float* __restrict__ Whh2,
    const float* __restrict__ bih2, const float* __restrict__ bhh2,
    _Float16* __restrict__ B0, _Float16* __restrict__ B1, _Float16* __restrict__ B2,
    float* __restrict__ W0p, float* __restrict__ biasP)
{
  size_t e = (size_t)blockIdx.x * 256 + threadIdx.x;
  const size_t S0 = (size_t)4096 * 1024;
  const size_t S1 = (size_t)4096 * 2048;
  if (e < S0) {
    int n = (int)(e >> 10), k = (int)(e & 1023);
    int nb = n >> 6, gate = (n >> 4) & 3, u = n & 15;
    int r = gate * 1024 + nb * 16 + u;
    B0[e] = (_Float16)Whh0[(size_t)r * 1024 + k];
  } else if (e < S0 + S1) {
    size_t q = e - S0;
    int n = (int)(q >> 11), k = (int)(q & 2047);
    int nb = n >> 6, gate = (n >> 4) & 3, u = n & 15;
    int r = gate * 1024 + nb * 16 + u;
    float v = (k < 1024) ? Wih1[(size_t)r * 1024 + k]
                         : Whh1[(size_t)r * 1024 + (k - 1024)];
    B1[q] = (_Float16)v;
  } else if (e < S0 + 2 * S1) {
    size_t q = e - S0 - S1;
    int n = (int)(q >> 11), k = (int)(q & 2047);
    int nb = n >> 6, gate = (n >> 4) & 3, u = n & 15;
    int r = gate * 1024 + nb * 16 + u;
    float v = (k < 1024) ? Wih2[(size_t)r * 1024 + k]
                         : Whh2[(size_t)r * 1024 + (k - 1024)];
    B2[q] = (_Float16)v;
  } else if (e < S0 + 2 * S1 + 40960) {
    int q = (int)(e - S0 - 2 * S1);
    int n = q / 10, k = q - n * 10;
    int nb = n >> 6, gate = (n >> 4) & 3, u = n & 15;
    int r = gate * 1024 + nb * 16 + u;
    W0p[q] = Wih0[(size_t)r * 10 + k];
  } else if (e < S0 + 2 * S1 + 40960 + 12288) {
    int q = (int)(e - S0 - 2 * S1 - 40960);
    int l = q >> 12, n = q & 4095;
    int nb = n >> 6, gate = (n >> 4) & 3, u = n & 15;
    int r = gate * 1024 + nb * 16 + u;
    const float* bi = (l == 0) ? bih0 : (l == 1) ? bih1 : bih2;
    const float* bh = (l == 0) ? bhh0 : (l == 1) ? bhh1 : bhh2;
    biasP[q] = bi[r] + bh[r];
  }
}

// ---------------------------------------------------------------------------
// Encoder wavefront kernel (unchanged): dispatch d = L0@t=d, L1@d-1, L2@d-2.
// ---------------------------------------------------------------------------
__global__ __launch_bounds__(256) void lstm_wave(
    int d,
    _Float16* __restrict__ h0p0, _Float16* __restrict__ h0p1,
    _Float16* __restrict__ h1p0, _Float16* __restrict__ h1p1,
    _Float16* __restrict__ h2p0, _Float16* __restrict__ h2p1,
    const _Float16* __restrict__ B0g, const _Float16* __restrict__ B1g,
    const _Float16* __restrict__ B2g,
    const float* __restrict__ biasP, const float* __restrict__ W0p,
    float* __restrict__ c0, float* __restrict__ c1, float* __restrict__ c2,
    const float* __restrict__ x, const int* __restrict__ xte,
    const float* __restrict__ e0, const float* __restrict__ e1,
    const float* __restrict__ e2, const float* __restrict__ e3)
{
  __shared__ __align__(16) char smem[32768];
  __shared__ float SmallIn[BM * SK];
  __shared__ float W0s[BN * 11];

  const int layer = blockIdx.y >> 2;
  const int mb = blockIdx.y & 3, nb = blockIdx.x;
  const int t = d - layer;
  if (t < 0 || t >= TSEQ) return;
  const int p = d & 1;

  const _Float16 *A1, *A2; _Float16* ho; const _Float16* Bm;
  const float* bias; float* cst; int Kdim;
  if (layer == 0) {
    A1 = p ? h0p1 : h0p0; A2 = A1;              ho = p ? h0p0 : h0p1;
    Bm = B0g; bias = biasP;        cst = c0; Kdim = 1024;
  } else if (layer == 1) {
    A1 = p ? h0p1 : h0p0; A2 = p ? h1p1 : h1p0; ho = p ? h1p0 : h1p1;
    Bm = B1g; bias = biasP + 4096; cst = c1; Kdim = 2048;
  } else {
    A1 = p ? h1p1 : h1p0; A2 = p ? h2p1 : h2p0; ho = p ? h2p0 : h2p1;
    Bm = B2g; bias = biasP + 8192; cst = c2; Kdim = 2048;
  }
  const int Mbase = mb * BM;
  const int tid = threadIdx.x;

  if (layer == 0 && tid < BM) {
    int Mg = Mbase + tid;
    float v[SK];
    const float* xp = x + ((size_t)Mg * TSEQ + t) * IND;
#pragma unroll
    for (int i = 0; i < IND; ++i) v[i] = xp[i];
    const int* ip = xte + ((size_t)Mg * TSEQ + t) * 4;
    int i0 = ip[0], i1 = ip[1], i2 = ip[2], i3 = ip[3];
#pragma unroll
    for (int dd = 0; dd < 3; ++dd)
      v[IND + dd] = e0[i0 * 3 + dd] + e1[i1 * 3 + dd] + e2[i2 * 3 + dd] + e3[i3 * 3 + dd];
#pragma unroll
    for (int i = 0; i < SK; ++i) SmallIn[tid * SK + i] = v[i];
    const float* wp = W0p + (size_t)(nb * BN + tid) * SK;
#pragma unroll
    for (int i = 0; i < SK; ++i) W0s[tid * 11 + i] = wp[i];
  }

  _Float16* As = (_Float16*)smem;
  _Float16* Bs = (_Float16*)(smem + 16384);

  const int w = tid >> 6, lane = tid & 63;
  const int quad = lane >> 4, l16 = lane & 15;
  const int dr = lane >> 4, ds = lane & 15;

  size_t a_goff[4], b_goff[4];
  int lds_off[4];
#pragma unroll
  for (int i = 0; i < 4; ++i) {
    int lrow = w * 16 + i * 4 + dr;
    int sg = ds ^ (i * 4 + dr);
    a_goff[i] = (size_t)(Mbase + lrow) * (HID * 2) + (size_t)sg * 16;
    b_goff[i] = (size_t)(nb * BN + lrow) * ((size_t)Kdim * 2) + (size_t)sg * 16;
    lds_off[i] = lrow * 256 + ds * 16;
  }

  f32x4 acc[4] = {};

  for (int kk = 0; kk < Kdim; kk += 128) {
    const char* Abase = (kk < 1024)
        ? ((const char*)A1 + (size_t)kk * 2)
        : ((const char*)A2 + (size_t)(kk - 1024) * 2);
    const char* Bbase = (const char*)Bm + (size_t)kk * 2;
#pragma unroll
    for (int i = 0; i < 4; ++i) {
      async_cp16<0>(Abase + a_goff[i], smem + lds_off[i]);
      async_cp16<0>(Bbase + b_goff[i], smem + 16384 + lds_off[i]);
    }
    __syncthreads();
#pragma unroll
    for (int ks = 0; ks < 4; ++ks) {
      int segq = (ks * 4 + quad) ^ l16;
      f16x8 bf = *reinterpret_cast<const f16x8*>(Bs + (w * 16 + l16) * 128 + segq * 8);
#pragma unroll
      for (int mt = 0; mt < 4; ++mt) {
        f16x8 af = *reinterpret_cast<const f16x8*>(As + (mt * 16 + l16) * 128 + segq * 8);
        acc[mt] = __builtin_amdgcn_mfma_f32_16x16x32_f16(af, bf, acc[mt], 0, 0, 0);
      }
    }
    __syncthreads();
  }

  float* Gs = (float*)smem;
#pragma unroll
  for (int mt = 0; mt < 4; ++mt) {
    int row = mt * 16 + quad * 4;
    int col = w * 16 + l16;
#pragma unroll
    for (int r = 0; r < 4; ++r)
      Gs[(row + r) * GSTR + col] = acc[mt][r];
  }
  __syncthreads();

#pragma unroll
  for (int i = 0; i < 4; ++i) {
    int m = (tid >> 4) + i * 16;
    int u = tid & 15;
    float gi = Gs[m * GSTR + u];
    float gf = Gs[m * GSTR + 16 + u];
    float gg = Gs[m * GSTR + 32 + u];
    float go = Gs[m * GSTR + 48 + u];
    int nbase = nb * BN;
    gi += bias[nbase + u];
    gf += bias[nbase + 16 + u];
    gg += bias[nbase + 32 + u];
    go += bias[nbase + 48 + u];
    if (layer == 0) {
#pragma unroll
      for (int k = 0; k < SK; ++k) {
        float sv = SmallIn[m * SK + k];
        gi += sv * W0s[u * 11 + k];
        gf += sv * W0s[(16 + u) * 11 + k];
        gg += sv * W0s[(32 + u) * 11 + k];
        go += sv * W0s[(48 + u) * 11 + k];
      }
    }
    size_t cidx = (size_t)(Mbase + m) * HID + (size_t)nb * 16 + u;
    float cold = cst[cidx];
    float cn = sigmoidf_fast(gf) * cold + sigmoidf_fast(gi) * tanhf_fast(gg);
    float hn = sigmoidf_fast(go) * tanhf_fast(cn);
    cst[cidx] = cn;
    ho[cidx] = (_Float16)hn;
  }
}

// ---------------------------------------------------------------------------
// Decoder phase kernel v10: 64x64 tile, 512 threads/block, K-chunk = 256
// (8 iterations deep, 4 for L0 - halves the ~0.5us/iter fixed cost), ring-2
// x 64KB slots, 2x per-block staging in flight vs the 256-thread variants.
// Kernel-boundary coherence (v6-proven, plain cached ops). Grid (64 nb, 4 mb)
// = 256 blocks, 134KB LDS -> 1 block/CU, all resident.
// LDS dst is linear (wave-uniform base + lane*16); the 16B-seg XOR swizzle
// rides on the pre-swizzled global source (HW-compliant, v6-proven pattern).
// MODE 1: L0 (KC=4, +small input). MODE 2: deep. MODE 3: deep + fused fc.
// ---------------------------------------------------------------------------
template<int KC, int MODE>   // KC = K/256 chunks: 4 (L0) or 8 (deep)
__global__ __launch_bounds__(512, 2) void dec_phase(
    const _Float16* __restrict__ A1g, const _Float16* __restrict__ A2g,
    _Float16* __restrict__ ho, const _Float16* __restrict__ Bm,
    const float* __restrict__ biasL, const float* __restrict__ W0p,
    float* __restrict__ cst, float* __restrict__ out,
    const int* __restrict__ yte,
    const float* __restrict__ e0, const float* __restrict__ e1,
    const float* __restrict__ e2, const float* __restrict__ e3,
    const float* __restrict__ fcW, const float* __restrict__ fcb, int s)
{
  __shared__ __align__(16) char smem[2 * 65536];   // ring-2: A 32KB + B 32KB
  __shared__ float SmallIn[64 * SK];
  __shared__ float W0s[64 * 11];
  // gates buffer aliases slot 0 (ring fully drained before epilogue)
  float* Gs = (float*)smem;                        // 64*68*4 = 17.4KB

  const int tid = threadIdx.x;
  const int nb = blockIdx.x, mb = blockIdx.y;
  const int Mbase = mb * 64;

  if (MODE == 1) {
    if (tid < 64) {
      int Mg = Mbase + tid;
      float v[SK];
      const float* yp = out + (size_t)Mg * (PRED * OUTD) + s * OUTD;
#pragma unroll
      for (int i = 0; i < OUTD; ++i) v[i] = yp[i];   // plain loads: boundary-coherent
      const int* ip = yte + ((size_t)Mg * PRED + s) * 4;
      int i0 = ip[0], i1 = ip[1], i2 = ip[2], i3 = ip[3];
#pragma unroll
      for (int dd = 0; dd < 3; ++dd)
        v[IND + dd] = e0[i0 * 3 + dd] + e1[i1 * 3 + dd]
                    + e2[i2 * 3 + dd] + e3[i3 * 3 + dd];
#pragma unroll
      for (int i = 0; i < SK; ++i) SmallIn[tid * SK + i] = v[i];
      const float* wp = W0p + (size_t)(nb * 64 + tid) * SK;
#pragma unroll
      for (int i = 0; i < SK; ++i) W0s[tid * 11 + i] = wp[i];
    }
  }

  const int w = tid >> 6, lane = tid & 63;
  const int quad = lane >> 4, l16 = lane & 15;
  const int rowh = w >> 2, colw = w & 3;   // wave's M-half and N-quarter

  // staging source offsets: slot j = op*512 + tid -> row = j>>5 (64 rows of
  // 512B), seg = j&31; source seg = seg ^ (row&15) (16B XOR swizzle).
  // LDS dst = j*16 (linear). h row stride 2048B; B row stride KC*512B.
  int a_src[4], b_src[4];
#pragma unroll
  for (int op = 0; op < 4; ++op) {
    int j = op * 512 + tid, row = j >> 5, seg = j & 31;
    int sw = (seg ^ (row & 15)) * 16;
    a_src[op] = (Mbase + row) * 2048 + sw;
    b_src[op] = (nb * 64 + row) * (KC * 512) + sw;
  }
  const int dstb = tid * 16;

#define PISSUE(c) do { \
    const char* Ab_ = (KC == 4 || (c) < 4) \
        ? ((const char*)A1g + (size_t)(c) * 512) \
        : ((const char*)A2g + (size_t)((c) - 4) * 512); \
    const char* Bb_ = (const char*)Bm + (size_t)(c) * 512; \
    char* L_ = smem + ((c) & 1) * 65536; \
    _Pragma("unroll") \
    for (int i_ = 0; i_ < 4; ++i_) { \
      async_cp16<0>(Ab_ + a_src[i_], L_ + i_ * 8192 + dstb); \
      async_cp16<0>(Bb_ + b_src[i_], L_ + 32768 + i_ * 8192 + dstb); \
    } } while (0)

  f32x4 acc[2] = {};
  PISSUE(0);
#pragma unroll
  for (int c = 0; c < KC; ++c) {
    if (c + 1 < KC) { PISSUE(c + 1); WBAR(8); }   // chunk c drained, c+1 in flight
    else            { WBAR(0); }
    const _Float16* As = (const _Float16*)(smem + (c & 1) * 65536);
    const _Float16* Bs = As + 16384;               // +32KB in halfs
#pragma unroll
    for (int ks = 0; ks < 8; ++ks) {
      int sq = (ks * 4 + quad) ^ l16;              // seg in [0,32), row&15 = l16
      f16x8 bf = *reinterpret_cast<const f16x8*>(Bs + (colw * 16 + l16) * 256 + sq * 8);
      f16x8 a0 = *reinterpret_cast<const f16x8*>(As + (rowh * 32 + l16) * 256 + sq * 8);
      f16x8 a1 = *reinterpret_cast<const f16x8*>(As + (rowh * 32 + 16 + l16) * 256 + sq * 8);
      acc[0] = __builtin_amdgcn_mfma_f32_16x16x32_f16(a0, bf, acc[0], 0, 0, 0);
      acc[1] = __builtin_amdgcn_mfma_f32_16x16x32_f16(a1, bf, acc[1], 0, 0, 0);
    }
    BARO();   // ring-slot recycle guard
  }
#undef PISSUE

  // epilogue: gates transpose via LDS (ring drained -> Gs alias safe),
  // pointwise, h/c plain stores
#pragma unroll
  for (int mt = 0; mt < 2; ++mt) {
    int row = rowh * 32 + mt * 16 + quad * 4;
    int col = colw * 16 + l16;
#pragma unroll
    for (int r = 0; r < 4; ++r)
      Gs[(row + r) * GSTR + col] = acc[mt][r];
  }
  __syncthreads();

  const int u = tid & 15, mr = tid >> 4;   // mr 0..31
#pragma unroll
  for (int i = 0; i < 2; ++i) {
    int m = mr + i * 32;
    int nbase = nb * 64;
    float gi = Gs[m * GSTR + u]      + biasL[nbase + u];
    float gf = Gs[m * GSTR + 16 + u] + biasL[nbase + 16 + u];
    float gg = Gs[m * GSTR + 32 + u] + biasL[nbase + 32 + u];
    float go = Gs[m * GSTR + 48 + u] + biasL[nbase + 48 + u];
    if (MODE == 1) {
#pragma unroll
      for (int k = 0; k < SK; ++k) {
        float sv = SmallIn[m * SK + k];
        gi += sv * W0s[u * 11 + k];
        gf += sv * W0s[(16 + u) * 11 + k];
        gg += sv * W0s[(32 + u) * 11 + k];
        go += sv * W0s[(48 + u) * 11 + k];
      }
    }
    size_t cidx = (size_t)(Mbase + m) * HID + (size_t)nb * 16 + u;
    float cold = cst[cidx];
    float cn = sigmoidf_fast(gf) * cold + sigmoidf_fast(gi) * tanhf_fast(gg);
    float hn = sigmoidf_fast(go) * tanhf_fast(cn);
    cst[cidx] = cn;
    ho[cidx] = (_Float16)hn;
    if (MODE == 3) {
#pragma unroll
      for (int o = 0; o < OUTD; ++o) {
        float r = hn * fcW[(size_t)o * HID + nb * 16 + u];
        r += __shfl_xor(r, 1, 16);
        r += __shfl_xor(r, 2, 16);
        r += __shfl_xor(r, 4, 16);
        r += __shfl_xor(r, 8, 16);
        if (u == 0)
          atomicAdd(&out[(size_t)(Mbase + m) * (PRED * OUTD) + (s + 1) * OUTD + o],
                    r + ((nb == 0) ? fcb[o] : 0.0f));
      }
    }
  }
}

// ---------------------------------------------------------------------------
// Standalone FC head for y0 only: y = h2 @ fcW^T + fcb -> out[:,0,:].
// ---------------------------------------------------------------------------
__global__ __launch_bounds__(256) void fc_kernel(
    const _Float16* __restrict__ h2, const float* __restrict__ fcW,
    const float* __restrict__ fcb, float* __restrict__ out)
{
  int wv = threadIdx.x >> 6, lane = threadIdx.x & 63;
  int row = blockIdx.x * 4 + wv;
  const _Float16* hp = h2 + (size_t)row * HID + lane * 16;
  float hv[16];
#pragma unroll
  for (int i = 0; i < 16; ++i) hv[i] = (float)hp[i];
  float acc[OUTD];
#pragma unroll
  for (int o = 0; o < OUTD; ++o) {
    const float* wp = fcW + (size_t)o * HID + lane * 16;
    float a = 0.f;
#pragma unroll
    for (int i = 0; i < 16; ++i) a += hv[i] * wp[i];
    acc[o] = a;
  }
#pragma unroll
  for (int o = 0; o < OUTD; ++o)
#pragma unroll
    for (int off = 32; off >= 1; off >>= 1)
      acc[o] += __shfl_xor(acc[o], off, 64);
  if (lane == 0) {
#pragma unroll
    for (int o = 0; o < OUTD; ++o)
      out[(size_t)row * (PRED * OUTD) + o] = acc[o] + fcb[o];
  }
}

// ---------------------------------------------------------------------------
// Workspace layout (bytes):
//   B0 @0 (8 MB) | B1 @8388608 (16 MB) | B2 @25165824 (16 MB)
//   W0p @41943040 | biasP @42106880
//   h par0 @42156032 (1.5 MB) + c @43728896 (3 MB)  } one memset
//   h par1 @46874624 (1.5 MB)                        } second memset
// ---------------------------------------------------------------------------
extern "C" void kernel_launch(void* const* d_in, const int* in_sizes, int n_in,
                              void* d_out, int out_size, void* d_ws, size_t ws_size,
                              hipStream_t stream) {
  const float* x   = (const float*)d_in[0];
  const int*   xte = (const int*)d_in[2];
  const int*   yte = (const int*)d_in[3];
  const float* e0  = (const float*)d_in[4];
  const float* e1  = (const float*)d_in[5];
  const float* e2  = (const float*)d_in[6];
  const float* e3  = (const float*)d_in[7];
  const float* Wih0 = (const float*)d_in[8];
  const float* Whh0 = (const float*)d_in[9];
  const float* bih0 = (const float*)d_in[10];
  const float* bhh0 = (const float*)d_in[11];
  const float* Wih1 = (const float*)d_in[12];
  const float* Whh1 = (const float*)d_in[13];
  const float* bih1 = (const float*)d_in[14];
  const float* bhh1 = (const float*)d_in[15];
  const float* Wih2 = (const float*)d_in[16];
  const float* Whh2 = (const float*)d_in[17];
  const float* bih2 = (const float*)d_in[18];
  const float* bhh2 = (const float*)d_in[19];
  const float* fcW = (const float*)d_in[20];
  const float* fcb = (const float*)d_in[21];
  float* out = (float*)d_out;

  char* ws = (char*)d_ws;
  _Float16* B0   = (_Float16*)(ws);
  _Float16* B1   = (_Float16*)(ws + 8388608);
  _Float16* B2   = (_Float16*)(ws + 25165824);
  float*    W0p  = (float*)(ws + 41943040);
  float*    biasP= (float*)(ws + 42106880);
  char*     hp0  = ws + 42156032;
  float*    cbuf = (float*)(ws + 43728896);
  char*     hp1  = ws + 46874624;

  hipMemsetAsync(out, 0, (size_t)out_size * 4, stream);
  hipMemsetAsync(hp0, 0, 4718592, stream);
  hipMemsetAsync(hp1, 0, 1572864, stream);

  prep_kernel<<<82128, 256, 0, stream>>>(Wih0, Whh0, bih0, bhh0,
                                         Wih1, Whh1, bih1, bhh1,
                                         Wih2, Whh2, bih2, bhh2,
                                         B0, B1, B2, W0p, biasP);

  auto hb = [&](int l, int par) -> _Float16* {
    return (_Float16*)((par ? hp1 : hp0) + (size_t)l * 524288);
  };
  float* cl[3] = {cbuf, cbuf + 262144, cbuf + 524288};

  // encoder: wavefront over (layer, t) diagonals
  for (int d = 0; d < TSEQ + 2; ++d) {
    lstm_wave<<<dim3(64, 12), 256, 0, stream>>>(
        d, hb(0,0), hb(0,1), hb(1,0), hb(1,1), hb(2,0), hb(2,1),
        B0, B1, B2, biasP, W0p, cl[0], cl[1], cl[2],
        x, xte, e0, e1, e2, e3);
  }

  // handoff parities: h0@127 -> par0, h1@127 -> par1, h2@127 -> par0
  fc_kernel<<<64, 256, 0, stream>>>(hb(2,0), fcW, fcb, out);   // y0

  // decoder: 95 steps x 3 layer-phase dispatches, kernel-boundary coherence
  int p0 = 0, p1 = 1, p2 = 0;
  const dim3 dgrid(64, 4);
  for (int s = 0; s < PRED - 1; ++s) {
    dec_phase<4, 1><<<dgrid, 512, 0, stream>>>(
        hb(0, p0), hb(0, p0), hb(0, 1 - p0), B0,
        biasP, W0p, cl[0], out, yte, e0, e1, e2, e3, fcW, fcb, s);
    dec_phase<8, 2><<<dgrid, 512, 0, stream>>>(
        hb(0, 1 - p0), hb(1, p1), hb(1, 1 - p1), B1,
        biasP + 4096, W0p, cl[1], out, yte, e0, e1, e2, e3, fcW, fcb, s);
    dec_phase<8, 3><<<dgrid, 512, 0, stream>>>(
        hb(1, 1 - p1), hb(2, p2), hb(2, 1 - p2), B2,
        biasP + 8192, W0p, cl[2], out, yte, e0, e1, e2, e3, fcW, fcb, s);
    p0 ^= 1; p1 ^= 1; p2 ^= 1;
  }
}